// Round 2
// baseline (339.558 us; speedup 1.0000x reference)
//
#include <hip/hip_runtime.h>
#include <hip/hip_bf16.h>

// Problem constants (B=1, N=2048, D=1024, H=16, HD=64; NO=74 offsets)
#define SEQ_N 2048
#define DIM   1024
#define NHEAD 16
#define HDIM  64
#define LDQ   4096   // qkvg row stride: [q(1024) | k(1024) | v(1024) | gatepre(1024)]

typedef __attribute__((ext_vector_type(8))) __bf16 bv8;
typedef __attribute__((ext_vector_type(4))) __bf16 bv4;
typedef __attribute__((ext_vector_type(4))) float  f32x4;

typedef __attribute__((address_space(3))) void as3_void;
typedef __attribute__((address_space(1))) void as1_void;

// async global->LDS 16B copy. LDS dest must be wave-uniform base + lane*16.
__device__ __forceinline__ void async16(const void* g, void* l) {
  __builtin_amdgcn_global_load_lds((as1_void*)(unsigned long long)g,
                                   (as3_void*)l, 16, 0, 0);
}

// ---------------------------------------------------------------------------
// fp32 -> bf16 convert (n must be a multiple of 4)
// ---------------------------------------------------------------------------
__global__ __launch_bounds__(256) void cvt_f32_bf16(
    const float* __restrict__ src, __bf16* __restrict__ dst, int n) {
  int i = (blockIdx.x * 256 + threadIdx.x) * 4;
  if (i < n) {
    float4 v = *(const float4*)(src + i);
    bv4 o;
    o[0] = (__bf16)v.x; o[1] = (__bf16)v.y; o[2] = (__bf16)v.z; o[3] = (__bf16)v.w;
    *(bv4*)(dst + i) = o;
  }
}

// ---------------------------------------------------------------------------
// GEMM: C[M x Nout] = A[M x K] * B[Nout x K]^T + bias (fp32 bias), bf16 in,
// fp32 accum, OutT out. B split at col Nsplit: cols < Nsplit use B1/bias1,
// else B2/bias2. 128x128 tile, BK=32, 4 waves 2x2, each wave 64x64 via 4x4
// grid of 16x16x32 MFMA.
// ---------------------------------------------------------------------------
#define BM 128
#define BN 128
#define BK 32

template <typename OutT>
__global__ __launch_bounds__(256) void gemm_bt(
    const __bf16* __restrict__ A, const __bf16* __restrict__ B1,
    const __bf16* __restrict__ B2, const float* __restrict__ bias1,
    const float* __restrict__ bias2, int Nsplit,
    OutT* __restrict__ C, int ldc, int K) {
  __shared__ __bf16 Asm[BM * BK];   // 8 KB
  __shared__ __bf16 Bsm[BN * BK];   // 8 KB

  const int tid  = threadIdx.x;
  const int lane = tid & 63;
  const int wave = tid >> 6;
  const int wr = wave >> 1, wc = wave & 1;     // 2x2 wave grid
  const int fr = lane & 15, fq = lane >> 4;    // fragment row / quad

  const int bn0 = blockIdx.x * BN;
  const int bm0 = blockIdx.y * BM;

  const __bf16* Bp;
  const float* biasp;
  if (bn0 < Nsplit) { Bp = B1 + (size_t)bn0 * K;            biasp = bias1 + bn0; }
  else              { Bp = B2 + (size_t)(bn0 - Nsplit) * K; biasp = bias2 + (bn0 - Nsplit); }
  const __bf16* Ap = A + (size_t)bm0 * K;

  f32x4 acc[4][4] = {};

  // staging: 512 chunks of 16B per tile; thread t does chunks t and t+256.
  const int c0 = tid, c1 = tid + 256;
  const int r0 = c0 >> 2, q0 = c0 & 3;
  const int r1 = c1 >> 2, q1 = c1 & 3;

  for (int kt = 0; kt < K; kt += BK) {
    __syncthreads();   // protect LDS from previous iteration's readers
    async16(Ap + (size_t)r0 * K + kt + q0 * 8, Asm + c0 * 8);
    async16(Ap + (size_t)r1 * K + kt + q1 * 8, Asm + c1 * 8);
    async16(Bp + (size_t)r0 * K + kt + q0 * 8, Bsm + c0 * 8);
    async16(Bp + (size_t)r1 * K + kt + q1 * 8, Bsm + c1 * 8);
    __syncthreads();   // drains vmcnt -> LDS writes visible

    bv8 af[4], bfr[4];
#pragma unroll
    for (int i = 0; i < 4; ++i)
      af[i] = *(const bv8*)(Asm + (wr * 64 + i * 16 + fr) * BK + fq * 8);
#pragma unroll
    for (int j = 0; j < 4; ++j)
      bfr[j] = *(const bv8*)(Bsm + (wc * 64 + j * 16 + fr) * BK + fq * 8);
#pragma unroll
    for (int i = 0; i < 4; ++i)
#pragma unroll
      for (int j = 0; j < 4; ++j)
        acc[i][j] = __builtin_amdgcn_mfma_f32_16x16x32_bf16(af[i], bfr[j], acc[i][j], 0, 0, 0);
  }

  // Epilogue: C/D layout col = lane&15, row = (lane>>4)*4 + reg
#pragma unroll
  for (int i = 0; i < 4; ++i) {
#pragma unroll
    for (int j = 0; j < 4; ++j) {
      int ccol = wc * 64 + j * 16 + fr;
      float b = biasp[ccol];
#pragma unroll
      for (int r = 0; r < 4; ++r) {
        int row = bm0 + wr * 64 + i * 16 + fq * 4 + r;
        C[(size_t)row * ldc + bn0 + ccol] = (OutT)(acc[i][j][r] + b);
      }
    }
  }
}

// ---------------------------------------------------------------------------
// Dyadic-offset attention + gate. One 128-thread block per (n, h).
// Threads 0..NO-1: score lanes (dot(q, k[n-off]) * scale + pos_bias).
// LDS softmax; threads 0..63: output dim lanes (sum_o p_o * v[n-off_o, d]),
// multiplied by sigmoid(gate_pre), written bf16 to fg[n, h*64+d].
// ---------------------------------------------------------------------------
__global__ __launch_bounds__(128) void attn_kernel(
    const __bf16* __restrict__ qkv,      // [SEQ_N x LDQ]
    const float* __restrict__ pos_bias,  // [NO x NHEAD] fp32
    const int* __restrict__ offsets,     // [NO]
    __bf16* __restrict__ fg, int NO) {
  const int n = blockIdx.x >> 4;
  const int h = blockIdx.x & 15;
  const int tid = threadIdx.x;

  __shared__ float qs[HDIM];
  __shared__ float sc[96];
  __shared__ float ps[96];
  __shared__ int   offs[96];

  if (tid < HDIM) qs[tid] = (float)qkv[(size_t)n * LDQ + h * HDIM + tid];
  if (tid < NO)   offs[tid] = offsets[tid];
  __syncthreads();

  float score = -3.0e38f;
  if (tid < NO) {
    int idx = n - offs[tid];
    if (idx >= 0) {
      const bv8* kv = (const bv8*)(qkv + (size_t)idx * LDQ + DIM + h * HDIM);
      float s = 0.f;
#pragma unroll
      for (int c = 0; c < 8; ++c) {
        bv8 kk = kv[c];
#pragma unroll
        for (int j = 0; j < 8; ++j) s += qs[c * 8 + j] * (float)kk[j];
      }
      score = s * 0.125f + pos_bias[tid * NHEAD + h];
    }
    sc[tid] = score;
  }
  __syncthreads();

  float mx = -3.0e38f;
  for (int o = 0; o < NO; ++o) mx = fmaxf(mx, sc[o]);
  if (tid < NO) ps[tid] = (sc[tid] > -1.0e38f) ? __expf(sc[tid] - mx) : 0.f;
  __syncthreads();

  if (tid < HDIM) {
    float ssum = 0.f;
    for (int o = 0; o < NO; ++o) ssum += ps[o];
    float acc = 0.f;
    for (int o = 0; o < NO; ++o) {
      int idx = n - offs[o];
      if (idx >= 0)
        acc += ps[o] * (float)qkv[(size_t)idx * LDQ + 2 * DIM + h * HDIM + tid];
    }
    float gpre = (float)qkv[(size_t)n * LDQ + 3 * DIM + h * HDIM + tid];
    float g = 1.f / (1.f + __expf(-gpre));
    fg[(size_t)n * DIM + h * HDIM + tid] = (__bf16)((acc / ssum) * g);
  }
}

// ---------------------------------------------------------------------------
extern "C" void kernel_launch(void* const* d_in, const int* in_sizes, int n_in,
                              void* d_out, int out_size, void* d_ws, size_t ws_size,
                              hipStream_t stream) {
  const float* x        = (const float*)d_in[0];
  const float* Wqkv     = (const float*)d_in[1];
  const float* bqkv     = (const float*)d_in[2];
  const float* Wgate    = (const float*)d_in[3];
  const float* bgate    = (const float*)d_in[4];
  const float* Wout     = (const float*)d_in[5];
  const float* bout     = (const float*)d_in[6];
  const float* pos_bias = (const float*)d_in[7];
  const int*   offsets  = (const int*)d_in[8];
  float* out = (float*)d_out;

  const int NO = in_sizes[8];

  // workspace layout (bf16 elements)
  __bf16* xb       = (__bf16*)d_ws;                               // 2048x1024
  __bf16* Wqkvb    = xb    + (size_t)SEQ_N * DIM;                 // 3072x1024
  __bf16* Wgateb   = Wqkvb + (size_t)3 * DIM * DIM;               // 1024x1024
  __bf16* Woutb    = Wgateb + (size_t)DIM * DIM;                  // 1024x1024
  __bf16* qkvg     = Woutb + (size_t)DIM * DIM;                   // 2048x4096
  __bf16* flatgate = qkvg + (size_t)SEQ_N * LDQ;                  // 2048x1024

  // 0) fp32 -> bf16 conversions
  {
    int n1 = SEQ_N * DIM;        // x
    int n2 = 3 * DIM * DIM;      // Wqkv
    int n3 = DIM * DIM;          // Wgate / Wout
    cvt_f32_bf16<<<dim3(n1 / 1024), dim3(256), 0, stream>>>(x, xb, n1);
    cvt_f32_bf16<<<dim3(n2 / 1024), dim3(256), 0, stream>>>(Wqkv, Wqkvb, n2);
    cvt_f32_bf16<<<dim3(n3 / 1024), dim3(256), 0, stream>>>(Wgate, Wgateb, n3);
    cvt_f32_bf16<<<dim3(n3 / 1024), dim3(256), 0, stream>>>(Wout, Woutb, n3);
  }

  // 1) [qkv | gate_pre] = x @ [Wqkv;Wgate]^T + [bqkv;bgate]  -> bf16 qkvg
  gemm_bt<__bf16><<<dim3(LDQ / BN, SEQ_N / BM), dim3(256), 0, stream>>>(
      xb, Wqkvb, Wgateb, bqkv, bgate, 3 * DIM, qkvg, LDQ, DIM);

  // 2) attention + sigmoid-gate fuse -> flatgate (bf16)
  attn_kernel<<<dim3(SEQ_N * NHEAD), dim3(128), 0, stream>>>(
      qkvg, pos_bias, offsets, flatgate, NO);

  // 3) out = flatgate @ Wout^T + bout  -> fp32 d_out
  gemm_bt<float><<<dim3(DIM / BN, SEQ_N / BM), dim3(256), 0, stream>>>(
      flatgate, Woutb, Woutb, bout, bout, 1 << 30, out, DIM, DIM);
}

// Round 3
// 213.484 us; speedup vs baseline: 1.5906x; 1.5906x over previous
//
#include <hip/hip_runtime.h>
#include <hip/hip_bf16.h>

// Problem constants (B=1, N=2048, D=1024, H=16, HD=64; NO=74 offsets)
#define SEQ_N 2048
#define DIM   1024
#define NHEAD 16
#define HDIM  64
#define LDQ   4096   // qkvg row stride: [q(1024) | k(1024) | v(1024) | gatepre(1024)]
#define NOFF  74     // 65 dense (0..64) + 9 dyadic

typedef __attribute__((ext_vector_type(8))) __bf16 bv8;
typedef __attribute__((ext_vector_type(4))) __bf16 bv4;
typedef __attribute__((ext_vector_type(4))) float  f32x4;

typedef __attribute__((address_space(3))) void as3_void;
typedef __attribute__((address_space(1))) void as1_void;

// async global->LDS 16B copy. LDS dest must be wave-uniform base + lane*16.
__device__ __forceinline__ void async16(const void* g, void* l) {
  __builtin_amdgcn_global_load_lds((as1_void*)(unsigned long long)g,
                                   (as3_void*)l, 16, 0, 0);
}

// ---------------------------------------------------------------------------
// fp32 -> bf16 convert (n must be a multiple of 4)
// ---------------------------------------------------------------------------
__global__ __launch_bounds__(256) void cvt_f32_bf16(
    const float* __restrict__ src, __bf16* __restrict__ dst, int n) {
  int i = (blockIdx.x * 256 + threadIdx.x) * 4;
  if (i < n) {
    float4 v = *(const float4*)(src + i);
    bv4 o;
    o[0] = (__bf16)v.x; o[1] = (__bf16)v.y; o[2] = (__bf16)v.z; o[3] = (__bf16)v.w;
    *(bv4*)(dst + i) = o;
  }
}

// ---------------------------------------------------------------------------
// GEMM: C[M x Nout] = A[M x K] * B[Nout x K]^T + bias (fp32 bias), bf16 in,
// fp32 accum, OutT out. B split at col Nsplit. 128x128 tile, BK=32, 4 waves
// 2x2, each wave 64x64 via 4x4 grid of 16x16x32 MFMA.  (m97 structure)
// ---------------------------------------------------------------------------
#define BM 128
#define BN 128
#define BK 32

template <typename OutT>
__global__ __launch_bounds__(256) void gemm_bt(
    const __bf16* __restrict__ A, const __bf16* __restrict__ B1,
    const __bf16* __restrict__ B2, const float* __restrict__ bias1,
    const float* __restrict__ bias2, int Nsplit,
    OutT* __restrict__ C, int ldc, int K) {
  __shared__ __bf16 Asm[BM * BK];   // 8 KB
  __shared__ __bf16 Bsm[BN * BK];   // 8 KB

  const int tid  = threadIdx.x;
  const int lane = tid & 63;
  const int wave = tid >> 6;
  const int wr = wave >> 1, wc = wave & 1;
  const int fr = lane & 15, fq = lane >> 4;

  const int bn0 = blockIdx.x * BN;
  const int bm0 = blockIdx.y * BM;

  const __bf16* Bp;
  const float* biasp;
  if (bn0 < Nsplit) { Bp = B1 + (size_t)bn0 * K;            biasp = bias1 + bn0; }
  else              { Bp = B2 + (size_t)(bn0 - Nsplit) * K; biasp = bias2 + (bn0 - Nsplit); }
  const __bf16* Ap = A + (size_t)bm0 * K;

  f32x4 acc[4][4] = {};

  const int c0 = tid, c1 = tid + 256;
  const int r0 = c0 >> 2, q0 = c0 & 3;
  const int r1 = c1 >> 2, q1 = c1 & 3;

  for (int kt = 0; kt < K; kt += BK) {
    __syncthreads();
    async16(Ap + (size_t)r0 * K + kt + q0 * 8, Asm + c0 * 8);
    async16(Ap + (size_t)r1 * K + kt + q1 * 8, Asm + c1 * 8);
    async16(Bp + (size_t)r0 * K + kt + q0 * 8, Bsm + c0 * 8);
    async16(Bp + (size_t)r1 * K + kt + q1 * 8, Bsm + c1 * 8);
    __syncthreads();

    bv8 af[4], bfr[4];
#pragma unroll
    for (int i = 0; i < 4; ++i)
      af[i] = *(const bv8*)(Asm + (wr * 64 + i * 16 + fr) * BK + fq * 8);
#pragma unroll
    for (int j = 0; j < 4; ++j)
      bfr[j] = *(const bv8*)(Bsm + (wc * 64 + j * 16 + fr) * BK + fq * 8);
#pragma unroll
    for (int i = 0; i < 4; ++i)
#pragma unroll
      for (int j = 0; j < 4; ++j)
        acc[i][j] = __builtin_amdgcn_mfma_f32_16x16x32_bf16(af[i], bfr[j], acc[i][j], 0, 0, 0);
  }

#pragma unroll
  for (int i = 0; i < 4; ++i) {
#pragma unroll
    for (int j = 0; j < 4; ++j) {
      int ccol = wc * 64 + j * 16 + fr;
      float b = biasp[ccol];
#pragma unroll
      for (int r = 0; r < 4; ++r) {
        int row = bm0 + wr * 64 + i * 16 + fq * 4 + r;
        C[(size_t)row * ldc + bn0 + ccol] = (OutT)(acc[i][j][r] + b);
      }
    }
  }
}

// ---------------------------------------------------------------------------
// Dyadic-offset attention + gate, restructured. One 128-thread block per
// (n, h). Lane mapping: dchunk = tid&7 (8 dims via bv8), og = tid>>3 (0..15).
// Phase 1: 5 rounds, o = r*16+og; 16B K load + 8 FMA; shfl_xor(1,2,4)
//   reduces dim-chunks -> sc[o].
// Phase 2: wave-shuffle softmax (max, sum) + 2-slot LDS cross-wave.
// Phase 3: 5 rounds of 16B V loads, fp32 accum[8]; shfl_xor(8,16,32) +
//   LDS cross-wave reduce over og; 8 threads apply sigmoid gate, store 16B.
// ---------------------------------------------------------------------------
__global__ __launch_bounds__(128) void attn_kernel(
    const __bf16* __restrict__ qkv,      // [SEQ_N x LDQ]
    const float* __restrict__ pos_bias,  // [NO x NHEAD] fp32
    const int* __restrict__ offsets,     // [NO]
    __bf16* __restrict__ fg) {
  const int n = blockIdx.x >> 4;
  const int h = blockIdx.x & 15;
  const int tid = threadIdx.x;
  const int wave = tid >> 6;
  const int dchunk = tid & 7;
  const int og = tid >> 3;

  __shared__ int   offs[NOFF];
  __shared__ float sc[80];
  __shared__ float ps[80];
  __shared__ float red[2];
  __shared__ float pv[2][64];

  if (tid < NOFF) offs[tid] = offsets[tid];
  __syncthreads();

  // preload q chunk (8 floats in registers)
  float qf[8];
  {
    bv8 qv = *(const bv8*)(qkv + (size_t)n * LDQ + h * HDIM + dchunk * 8);
#pragma unroll
    for (int j = 0; j < 8; ++j) qf[j] = (float)qv[j];
  }

  // ---- Phase 1: scores ----
  const __bf16* kbase = qkv + DIM + h * HDIM + dchunk * 8;
#pragma unroll
  for (int r = 0; r < 5; ++r) {
    int o = r * 16 + og;
    int idx = (o < NOFF) ? (n - offs[o]) : -1;
    float s = 0.f;
    if (idx >= 0) {
      bv8 kk = *(const bv8*)(kbase + (size_t)idx * LDQ);
#pragma unroll
      for (int j = 0; j < 8; ++j) s += qf[j] * (float)kk[j];
    }
    s += __shfl_xor(s, 1);
    s += __shfl_xor(s, 2);
    s += __shfl_xor(s, 4);
    if (dchunk == 0 && o < NOFF)
      sc[o] = (idx >= 0) ? s * 0.125f + pos_bias[o * NHEAD + h] : -3.0e38f;
  }
  __syncthreads();

  // ---- Phase 2: softmax ----
  float v0 = (tid < NOFF) ? sc[tid] : -3.0e38f;
  float m = v0;
#pragma unroll
  for (int d = 32; d >= 1; d >>= 1) m = fmaxf(m, __shfl_xor(m, d));
  if ((tid & 63) == 0) red[wave] = m;
  __syncthreads();
  float mx = fmaxf(red[0], red[1]);
  float e = (tid < NOFF && v0 > -1.0e38f) ? __expf(v0 - mx) : 0.f;
  if (tid < 80) ps[tid] = e;
  float s2 = e;
#pragma unroll
  for (int d = 32; d >= 1; d >>= 1) s2 += __shfl_xor(s2, d);
  __syncthreads();                 // everyone has read red; ps visible after next sync
  if ((tid & 63) == 0) red[wave] = s2;
  __syncthreads();
  float inv = 1.f / (red[0] + red[1]);

  // ---- Phase 3: PV + gate ----
  const __bf16* vbase = qkv + 2 * DIM + h * HDIM + dchunk * 8;
  float accf[8] = {};
#pragma unroll
  for (int r = 0; r < 5; ++r) {
    int o = r * 16 + og;
    int idx = (o < NOFF) ? (n - offs[o]) : -1;
    if (idx >= 0) {
      float p = ps[o];
      bv8 vv = *(const bv8*)(vbase + (size_t)idx * LDQ);
#pragma unroll
      for (int j = 0; j < 8; ++j) accf[j] += p * (float)vv[j];
    }
  }
#pragma unroll
  for (int d = 8; d <= 32; d <<= 1)
#pragma unroll
    for (int j = 0; j < 8; ++j) accf[j] += __shfl_xor(accf[j], d);
  if ((tid & 63) < 8) {
#pragma unroll
    for (int j = 0; j < 8; ++j) pv[wave][dchunk * 8 + j] = accf[j];
  }
  __syncthreads();
  if (tid < 8) {
    bv8 gp = *(const bv8*)(qkv + (size_t)n * LDQ + 3 * DIM + h * HDIM + tid * 8);
    bv8 outv;
#pragma unroll
    for (int j = 0; j < 8; ++j) {
      float sum = (pv[0][tid * 8 + j] + pv[1][tid * 8 + j]) * inv;
      float g = 1.f / (1.f + __expf(-(float)gp[j]));
      outv[j] = (__bf16)(sum * g);
    }
    *(bv8*)(fg + (size_t)n * DIM + h * HDIM + tid * 8) = outv;
  }
}

// ---------------------------------------------------------------------------
extern "C" void kernel_launch(void* const* d_in, const int* in_sizes, int n_in,
                              void* d_out, int out_size, void* d_ws, size_t ws_size,
                              hipStream_t stream) {
  const float* x        = (const float*)d_in[0];
  const float* Wqkv     = (const float*)d_in[1];
  const float* bqkv     = (const float*)d_in[2];
  const float* Wgate    = (const float*)d_in[3];
  const float* bgate    = (const float*)d_in[4];
  const float* Wout     = (const float*)d_in[5];
  const float* bout     = (const float*)d_in[6];
  const float* pos_bias = (const float*)d_in[7];
  const int*   offsets  = (const int*)d_in[8];
  float* out = (float*)d_out;

  // workspace layout (bf16 elements)
  __bf16* xb       = (__bf16*)d_ws;                               // 2048x1024
  __bf16* Wqkvb    = xb    + (size_t)SEQ_N * DIM;                 // 3072x1024
  __bf16* Wgateb   = Wqkvb + (size_t)3 * DIM * DIM;               // 1024x1024
  __bf16* Woutb    = Wgateb + (size_t)DIM * DIM;                  // 1024x1024
  __bf16* qkvg     = Woutb + (size_t)DIM * DIM;                   // 2048x4096
  __bf16* flatgate = qkvg + (size_t)SEQ_N * LDQ;                  // 2048x1024

  // 0) fp32 -> bf16 conversions
  {
    int n1 = SEQ_N * DIM;
    int n2 = 3 * DIM * DIM;
    int n3 = DIM * DIM;
    cvt_f32_bf16<<<dim3(n1 / 1024), dim3(256), 0, stream>>>(x, xb, n1);
    cvt_f32_bf16<<<dim3(n2 / 1024), dim3(256), 0, stream>>>(Wqkv, Wqkvb, n2);
    cvt_f32_bf16<<<dim3(n3 / 1024), dim3(256), 0, stream>>>(Wgate, Wgateb, n3);
    cvt_f32_bf16<<<dim3(n3 / 1024), dim3(256), 0, stream>>>(Wout, Woutb, n3);
  }

  // 1) [qkv | gate_pre] = x @ [Wqkv;Wgate]^T + [bqkv;bgate]  -> bf16 qkvg
  gemm_bt<__bf16><<<dim3(LDQ / BN, SEQ_N / BM), dim3(256), 0, stream>>>(
      xb, Wqkvb, Wgateb, bqkv, bgate, 3 * DIM, qkvg, LDQ, DIM);

  // 2) attention + sigmoid-gate fuse -> flatgate (bf16)
  attn_kernel<<<dim3(SEQ_N * NHEAD), dim3(128), 0, stream>>>(
      qkvg, pos_bias, offsets, flatgate);

  // 3) out = flatgate @ Wout^T + bout  -> fp32 d_out
  gemm_bt<float><<<dim3(DIM / BN, SEQ_N / BM), dim3(256), 0, stream>>>(
      flatgate, Woutb, Woutb, bout, bout, 1 << 30, out, DIM, DIM);
}

// Round 4
// 161.249 us; speedup vs baseline: 2.1058x; 1.3239x over previous
//
#include <hip/hip_runtime.h>
#include <hip/hip_bf16.h>

// Problem constants (B=1, N=2048, D=1024, H=16, HD=64; NO=74 offsets)
#define SEQ_N 2048
#define DIM   1024
#define NHEAD 16
#define HDIM  64
#define LDQ   4096   // qkvg row stride: [q | k | v | gatepre]
#define NOFF  74     // 65 dense (0..64) + 9 dyadic
#define NDENSE 65
#define NJ    224    // 80 dense rows + 9*16 dyadic rows
#define NT    16     // n-rows per attention block
#define PST   232    // Pd row stride (padded, 16B-aligned, 2-way-bank-safe)
#define QST   88     // Qbuf row stride (16B-aligned, 2-way-bank-safe)

typedef __attribute__((ext_vector_type(8))) __bf16 bv8;
typedef __attribute__((ext_vector_type(4))) __bf16 bv4;
typedef __attribute__((ext_vector_type(4))) float  f32x4;

typedef __attribute__((address_space(3))) void as3_void;
typedef __attribute__((address_space(1))) void as1_void;

// async global->LDS 16B copy. LDS dest must be wave-uniform base + lane*16.
__device__ __forceinline__ void async16(const void* g, void* l) {
  __builtin_amdgcn_global_load_lds((as1_void*)(unsigned long long)g,
                                   (as3_void*)l, 16, 0, 0);
}

// ---------------------------------------------------------------------------
// fp32 -> bf16 convert, all 4 tensors in one launch (dst regions contiguous).
// ---------------------------------------------------------------------------
#define E1 (SEQ_N * DIM)            // x
#define E2 (E1 + 3 * DIM * DIM)     // + Wqkv
#define E3 (E2 + DIM * DIM)         // + Wgate
#define E4 (E3 + DIM * DIM)         // + Wout
__global__ __launch_bounds__(256) void cvt_all(
    const float* __restrict__ x, const float* __restrict__ wqkv,
    const float* __restrict__ wgate, const float* __restrict__ wout,
    __bf16* __restrict__ dst) {
  long i = ((long)blockIdx.x * 256 + threadIdx.x) * 4;
  if (i >= E4) return;
  const float* s; long o;
  if (i < E1)      { s = x;     o = i; }
  else if (i < E2) { s = wqkv;  o = i - E1; }
  else if (i < E3) { s = wgate; o = i - E2; }
  else             { s = wout;  o = i - E3; }
  float4 v = *(const float4*)(s + o);
  bv4 ov;
  ov[0] = (__bf16)v.x; ov[1] = (__bf16)v.y; ov[2] = (__bf16)v.z; ov[3] = (__bf16)v.w;
  *(bv4*)(dst + i) = ov;
}

// ---------------------------------------------------------------------------
// GEMM: C[M x Nout] = A[M x K] * B[Nout x K]^T + bias (fp32), bf16 in, fp32
// accum, OutT out. Template BN_: 128 (2x2 waves of 64x64) or 64 (2x2 waves of
// 64x32). BM=128, BK=32. m97 structure.
// ---------------------------------------------------------------------------
#define BM 128
#define BK 32

template <int BN_, typename OutT>
__global__ __launch_bounds__(256) void gemm_bt(
    const __bf16* __restrict__ A, const __bf16* __restrict__ B1,
    const __bf16* __restrict__ B2, const float* __restrict__ bias1,
    const float* __restrict__ bias2, int Nsplit,
    OutT* __restrict__ C, int ldc, int K) {
  __shared__ __attribute__((aligned(16))) __bf16 Asm[BM * BK];
  __shared__ __attribute__((aligned(16))) __bf16 Bsm[BN_ * BK];
  constexpr int NJT = BN_ / 32;           // j-tiles per wave
  constexpr int CA = BM * BK / 8;         // A 16B-chunks
  constexpr int CB = BN_ * BK / 8;        // B 16B-chunks

  const int tid  = threadIdx.x;
  const int lane = tid & 63;
  const int wave = tid >> 6;
  const int wr = wave >> 1, wc = wave & 1;
  const int fr = lane & 15, fq = lane >> 4;

  const int bn0 = blockIdx.x * BN_;
  const int bm0 = blockIdx.y * BM;

  const __bf16* Bp;
  const float* biasp;
  if (bn0 < Nsplit) { Bp = B1 + (size_t)bn0 * K;            biasp = bias1 + bn0; }
  else              { Bp = B2 + (size_t)(bn0 - Nsplit) * K; biasp = bias2 + (bn0 - Nsplit); }
  const __bf16* Ap = A + (size_t)bm0 * K;

  f32x4 acc[4][NJT] = {};

  for (int kt = 0; kt < K; kt += BK) {
    __syncthreads();
#pragma unroll
    for (int c0 = 0; c0 < CA + CB; c0 += 256) {
      int c = c0 + tid;
      if (c < CA) {
        int rr = c >> 2, qq = c & 3;
        async16(Ap + (size_t)rr * K + kt + qq * 8, Asm + c * 8);
      } else {
        int cb = c - CA;
        int rr = cb >> 2, qq = cb & 3;
        async16(Bp + (size_t)rr * K + kt + qq * 8, Bsm + cb * 8);
      }
    }
    __syncthreads();

    bv8 af[4], bfr[NJT];
#pragma unroll
    for (int i = 0; i < 4; ++i)
      af[i] = *(const bv8*)(Asm + (wr * 64 + i * 16 + fr) * BK + fq * 8);
#pragma unroll
    for (int j = 0; j < NJT; ++j)
      bfr[j] = *(const bv8*)(Bsm + (wc * (BN_ / 2) + j * 16 + fr) * BK + fq * 8);
#pragma unroll
    for (int i = 0; i < 4; ++i)
#pragma unroll
      for (int j = 0; j < NJT; ++j)
        acc[i][j] = __builtin_amdgcn_mfma_f32_16x16x32_bf16(af[i], bfr[j], acc[i][j], 0, 0, 0);
  }

#pragma unroll
  for (int i = 0; i < 4; ++i) {
#pragma unroll
    for (int j = 0; j < NJT; ++j) {
      int ccol = wc * (BN_ / 2) + j * 16 + fr;
      float b = biasp[ccol];
#pragma unroll
      for (int r = 0; r < 4; ++r) {
        int row = bm0 + wr * 64 + i * 16 + fq * 4 + r;
        C[(size_t)row * ldc + bn0 + ccol] = (OutT)(acc[i][j][r] + b);
      }
    }
  }
}

// ---------------------------------------------------------------------------
// MFMA-tile attention + gate. One 256-thread block per (16-row n-tile, head).
// Kbuf/Vbuf rows j: 0..79 dense (g = n0-64+j), 80+16s+r dyadic
// (g = n0-off[65+s]+r). Scores = Q @ Kbuf^T via MFMA (banded entries
// scattered to Sbuf), softmax -> banded P (bf16) in Pd, PV = Pd @ Vbuf via
// MFMA, epilogue fuses 1/l and sigmoid gate.
// ---------------------------------------------------------------------------
__global__ __launch_bounds__(256) void attn_mfma(
    const __bf16* __restrict__ qkv,      // [SEQ_N x LDQ]
    const float* __restrict__ pos_bias,  // [NOFF x NHEAD]
    const int* __restrict__ offsets,     // [NOFF]
    __bf16* __restrict__ fg) {
  const int n0 = (blockIdx.x >> 4) * NT;
  const int h  = blockIdx.x & 15;
  const int tid = threadIdx.x;
  const int lane = tid & 63;
  const int w = tid >> 6;
  const int fr = lane & 15, fq = lane >> 4;

  __shared__ __attribute__((aligned(16))) __bf16 Kbuf[NJ * HDIM];   // 28672 B
  __shared__ __attribute__((aligned(16))) __bf16 Vbuf[NJ * HDIM];   // 28672 B
  __shared__ __attribute__((aligned(16))) __bf16 Qbuf[NT * QST];    // 2816 B
  __shared__ __attribute__((aligned(16))) float  Sbuf[NT][80];      // 5120 B
  __shared__ __attribute__((aligned(16))) __bf16 Pd[NT * PST];      // 7424 B
  __shared__ float inv_l[NT];

  // --- Phase 0: stage Q, zero Pd, async-stage K/V ---
  if (tid < 128) {
    int ni = tid >> 3, ch = tid & 7;
    bv8 q = *(const bv8*)(qkv + (size_t)(n0 + ni) * LDQ + h * HDIM + ch * 8);
    *(bv8*)(Qbuf + ni * QST + ch * 8) = q;
  }
#pragma unroll
  for (int c0 = 0; c0 < NT * PST / 8; c0 += 256) {
    int c = c0 + tid;
    if (c < NT * PST / 8) *(uint4*)(Pd + c * 8) = make_uint4(0, 0, 0, 0);
  }
  {
    int ch = lane & 7;
#pragma unroll
    for (int it = 0; it < 7; ++it) {
      int jbase = it * 32 + w * 8;
      int j = jbase + (lane >> 3);
      int g;
      if (j < 80) g = n0 - 64 + j;
      else { int jj = j - 80; g = n0 - offsets[NDENSE + (jj >> 4)] + (jj & 15); }
      if (g < 0) g = 0;   // clamp; masked later
      const __bf16* kg = qkv + (size_t)g * LDQ + DIM + h * HDIM + ch * 8;
      async16(kg, Kbuf + jbase * HDIM + lane * 8);
      async16(kg + DIM, Vbuf + jbase * HDIM + lane * 8);
    }
  }
  __syncthreads();

  // --- Phase 1: scores via MFMA, scatter banded entries to Sbuf ---
  for (int jb = w; jb < 14; jb += 4) {
    f32x4 acc = {};
#pragma unroll
    for (int kk = 0; kk < 2; ++kk) {
      bv8 a = *(const bv8*)(Qbuf + fr * QST + kk * 32 + fq * 8);
      bv8 b = *(const bv8*)(Kbuf + (jb * 16 + fr) * HDIM + kk * 32 + fq * 8);
      acc = __builtin_amdgcn_mfma_f32_16x16x32_bf16(a, b, acc, 0, 0, 0);
    }
    int j = jb * 16 + fr;           // Kbuf row this lane's column maps to
    if (jb < 5) {                   // dense region
      bool gvalid = (n0 - 64 + j) >= 0;
#pragma unroll
      for (int r = 0; r < 4; ++r) {
        int ni = fq * 4 + r;
        int o = ni + 64 - j;
        if (o >= 0 && o < NDENSE)
          Sbuf[ni][o] = gvalid ? acc[r] : -3.0e38f;
      }
    } else {                        // dyadic: only diagonal entries used
      int jj = j - 80;
      int s = jj >> 4, tni = jj & 15;
      int r = tni - fq * 4;
      if (r >= 0 && r < 4) {
        bool gvalid = (n0 + tni - offsets[NDENSE + s]) >= 0;
        Sbuf[tni][NDENSE + s] = gvalid ? acc[r] : -3.0e38f;
      }
    }
  }
  __syncthreads();

  // --- Phase 2: softmax (16 threads per row), banded P -> Pd (bf16) ---
  {
    int t = tid & 15, ni = tid >> 4;
    float sc5[5];
    float m = -3.0e38f;
#pragma unroll
    for (int k = 0; k < 5; ++k) {
      int o = t + k * 16;
      float v = -3.0e38f;
      if (o < NOFF) {
        float raw = Sbuf[ni][o];
        if (raw > -1.0e38f) v = raw * 0.125f + pos_bias[o * NHEAD + h];
      }
      sc5[k] = v;
      m = fmaxf(m, v);
    }
#pragma unroll
    for (int d = 1; d < 16; d <<= 1) m = fmaxf(m, __shfl_xor(m, d));
    float sum = 0.f;
#pragma unroll
    for (int k = 0; k < 5; ++k) {
      int o = t + k * 16;
      if (o < NOFF && sc5[k] > -1.0e38f) {
        float e = __expf(sc5[k] - m);
        sum += e;
        int j = (o < NDENSE) ? (ni + 64 - o) : (80 + (o - NDENSE) * 16 + ni);
        Pd[ni * PST + j] = (__bf16)e;
      }
    }
#pragma unroll
    for (int d = 1; d < 16; d <<= 1) sum += __shfl_xor(sum, d);
    if (t == 0) inv_l[ni] = 1.f / sum;
  }
  __syncthreads();

  // --- Phase 3: PV via MFMA (each wave one 16-col d-tile) + gate epilogue ---
  {
    const int db = w;
    f32x4 acc = {};
#pragma unroll
    for (int kt = 0; kt < 7; ++kt) {
      bv8 a = *(const bv8*)(Pd + fr * PST + kt * 32 + fq * 8);
      bv8 b;
#pragma unroll
      for (int jj = 0; jj < 8; ++jj)
        b[jj] = Vbuf[(kt * 32 + fq * 8 + jj) * HDIM + db * 16 + fr];
      acc = __builtin_amdgcn_mfma_f32_16x16x32_bf16(a, b, acc, 0, 0, 0);
    }
    int d = db * 16 + fr;
#pragma unroll
    for (int r = 0; r < 4; ++r) {
      int ni = fq * 4 + r;
      float o = acc[r] * inv_l[ni];
      float gp = (float)qkv[(size_t)(n0 + ni) * LDQ + 3 * DIM + h * HDIM + d];
      float gate = 1.f / (1.f + __expf(-gp));
      fg[(size_t)(n0 + ni) * DIM + h * HDIM + d] = (__bf16)(o * gate);
    }
  }
}

// ---------------------------------------------------------------------------
extern "C" void kernel_launch(void* const* d_in, const int* in_sizes, int n_in,
                              void* d_out, int out_size, void* d_ws, size_t ws_size,
                              hipStream_t stream) {
  const float* x        = (const float*)d_in[0];
  const float* Wqkv     = (const float*)d_in[1];
  const float* bqkv     = (const float*)d_in[2];
  const float* Wgate    = (const float*)d_in[3];
  const float* bgate    = (const float*)d_in[4];
  const float* Wout     = (const float*)d_in[5];
  const float* bout     = (const float*)d_in[6];
  const float* pos_bias = (const float*)d_in[7];
  const int*   offsets  = (const int*)d_in[8];
  float* out = (float*)d_out;

  // workspace layout (bf16), cvt dst regions contiguous in this order
  __bf16* xb       = (__bf16*)d_ws;                               // 2048x1024
  __bf16* Wqkvb    = xb    + (size_t)SEQ_N * DIM;                 // 3072x1024
  __bf16* Wgateb   = Wqkvb + (size_t)3 * DIM * DIM;               // 1024x1024
  __bf16* Woutb    = Wgateb + (size_t)DIM * DIM;                  // 1024x1024
  __bf16* qkvg     = Woutb + (size_t)DIM * DIM;                   // 2048x4096
  __bf16* flatgate = qkvg + (size_t)SEQ_N * LDQ;                  // 2048x1024

  // 0) fp32 -> bf16 (single launch)
  cvt_all<<<dim3(E4 / 1024), dim3(256), 0, stream>>>(x, Wqkv, Wgate, Wout, xb);

  // 1) [qkv | gate_pre] = x @ [Wqkv;Wgate]^T + [bqkv;bgate]  -> bf16 qkvg
  gemm_bt<128, __bf16><<<dim3(LDQ / 128, SEQ_N / BM), dim3(256), 0, stream>>>(
      xb, Wqkvb, Wgateb, bqkv, bgate, 3 * DIM, qkvg, LDQ, DIM);

  // 2) attention + sigmoid-gate fuse -> flatgate (bf16)
  attn_mfma<<<dim3((SEQ_N / NT) * NHEAD), dim3(256), 0, stream>>>(
      qkvg, pos_bias, offsets, flatgate);

  // 3) out = flatgate @ Wout^T + bout  -> fp32 d_out (BN=64: 256 blocks)
  gemm_bt<64, float><<<dim3(DIM / 64, SEQ_N / BM), dim3(256), 0, stream>>>(
      flatgate, Woutb, Woutb, bout, bout, 1 << 30, out, DIM, DIM);
}